// Round 9
// baseline (223.255 us; speedup 1.0000x reference)
//
#include <hip/hip_runtime.h>
#include <hip/hip_bf16.h>

#define K 128
#define NB 4096
#define EPW 4                    // examples per wave
#define WPB 2                    // waves per block (128 threads)
#define NBLK (NB / (EPW * WPB))  // 512 blocks -> 2 per CU
#define FW_ITERS 50

// ---------- DPP cross-lane helpers (validated rounds 3-8, absmax 0.0) ----------
template<int CTRL>
__device__ __forceinline__ float dpp_fmin(float v) {
    int s = __builtin_amdgcn_update_dpp(__float_as_int(v), __float_as_int(v), CTRL, 0xF, 0xF, false);
    return fminf(v, __int_as_float(s));
}
template<int CTRL>
__device__ __forceinline__ float dpp_fadd(float v) {
    int s = __builtin_amdgcn_update_dpp(__float_as_int(v), __float_as_int(v), CTRL, 0xF, 0xF, false);
    return v + __int_as_float(s);
}

__device__ __forceinline__ float wave_fmin_all(float v) {
    v = dpp_fmin<0xB1>(v);   // quad_perm xor1
    v = dpp_fmin<0x4E>(v);   // quad_perm xor2
    v = dpp_fmin<0x124>(v);  // row_ror:4
    v = dpp_fmin<0x128>(v);  // row_ror:8 -> per-16 min
#if __has_builtin(__builtin_amdgcn_permlane16_swap)
    {
        auto r = __builtin_amdgcn_permlane16_swap(__float_as_int(v), __float_as_int(v), false, false);
        v = fminf(__int_as_float(r[0]), __int_as_float(r[1]));
    }
#else
    v = fminf(v, __shfl_xor(v, 16, 64));
#endif
#if __has_builtin(__builtin_amdgcn_permlane32_swap)
    {
        auto r = __builtin_amdgcn_permlane32_swap(__float_as_int(v), __float_as_int(v), false, false);
        v = fminf(__int_as_float(r[0]), __int_as_float(r[1]));
    }
#else
    v = fminf(v, __shfl_xor(v, 32, 64));
#endif
    return v;
}

// per-32-lane-half sum (lanes 0-31 / 32-63 independently), result in all lanes
__device__ __forceinline__ float half_sum32(float v) {
    v = dpp_fadd<0xB1>(v);
    v = dpp_fadd<0x4E>(v);
    v = dpp_fadd<0x124>(v);
    v = dpp_fadd<0x128>(v);
#if __has_builtin(__builtin_amdgcn_permlane16_swap)
    {
        auto r = __builtin_amdgcn_permlane16_swap(__float_as_int(v), __float_as_int(v), false, false);
        v = __int_as_float(r[0]) + __int_as_float(r[1]);
    }
#else
    v = v + __shfl_xor(v, 16, 64);
#endif
    return v;
}

__device__ __forceinline__ unsigned short bf16_bits(float f) {
    __hip_bfloat16 h = __float2bfloat16(f);
    return *reinterpret_cast<unsigned short*>(&h);
}

// XOR swizzle: word(r, col) = col*64 + (r ^ swz(col)); word packs bf16 rows (2r,2r+1) at col.
// Build stores, FW column gather: <=2 lanes/bank (0 conflicts measured, r5/r6/r8).
__device__ __forceinline__ int swz(int col) {
    return ((col >> 2) + ((col & 3) << 3)) & 31;
}

__global__ __launch_bounds__(WPB * 64, 1) void cacis_main(
    const float* __restrict__ scores,
    const float* __restrict__ C,
    const int* __restrict__ targets,
    float* __restrict__ out_partial)
{
    // per-wave private regions: NO cross-wave communication, NO barriers anywhere
    __shared__ unsigned int Mw[WPB][K * 64];        // 2 x 32 KB swizzled pair-packed bf16
    __shared__ __align__(16) float s_l[WPB][K];
    __shared__ __align__(16) float grow[WPB][K];

    const int tid = threadIdx.x;
    const int w = tid >> 6;          // wave id within block
    const int l = tid & 63;
    const int half = l >> 5;         // 0: rows 2j, 1: rows 2j+1
    const int cb = 4 * (l & 31);     // owned column base
    const int exbase = blockIdx.x * (EPW * WPB) + w * EPW;

    // ---- prologue: this wave loads its first example (64 KB -> c[64]) ----
    float4 c[64];
    {
        const float* Cb = C + (size_t)exbase * (K * K);
        #pragma unroll
        for (int j = 0; j < 64; ++j)
            c[j] = *reinterpret_cast<const float4*>(Cb + 4 * l + 256 * j);
        s_l[w][l]      = scores[exbase * K + l];
        s_l[w][l + 64] = scores[exbase * K + 64 + l];
    }

    #pragma unroll 1
    for (int q = 0; q < EPW; ++q) {
        const int ex = exbase + q;
        const int tgt = targets[ex];             // wave-uniform scalar load
        const float f_y = s_l[w][tgt];           // same-wave LDS ordering via lgkmcnt

        // ---- pass 1: t = s_i + s_j + C; partials sumC / trace / min ----
        float sc0, sc1, sc2, sc3;
        {
            float4 s4 = *reinterpret_cast<const float4*>(&s_l[w][cb]);
            sc0 = s4.x; sc1 = s4.y; sc2 = s4.z; sc3 = s4.w;
        }
        float sumC = 0.f, trace = 0.f, minv = 1e30f;
        #pragma unroll
        for (int j = 0; j < 64; ++j) {
            const int row = 2 * j + half;        // lanes 0-31: row 2j; lanes 32-63: row 2j+1
            const float sr = s_l[w][row];
            float4 v = c[j];                     // vmcnt-ordered arrival
            sumC += (v.x + v.y) + (v.z + v.w);
            const int d = row - cb;
            if (d >= 0 && d < 4)
                trace += (d == 0) ? v.x : (d == 1) ? v.y : (d == 2) ? v.z : v.w;
            float t0 = sr + sc0 + v.x;
            float t1 = sr + sc1 + v.y;
            float t2 = sr + sc2 + v.z;
            float t3 = sr + sc3 + v.w;
            c[j] = make_float4(t0, t1, t2, t3);
            minv = fminf(minv, fminf(fminf(t0, t1), fminf(t2, t3)));
        }
        // wave-local reduce (no LDS, no barrier)
        #pragma unroll
        for (int m = 1; m < 64; m <<= 1) {
            sumC  += __shfl_xor(sumC, m, 64);
            trace += __shfl_xor(trace, m, 64);
            minv   = fminf(minv, __shfl_xor(minv, m, 64));
        }
        const float eps = fmaxf((sumC - trace) * (1.0f / (float)(K * (K - 1))), 1e-8f); // EPS_SCALE=1
        const float inv_eps = 1.0f / eps;

        // ---- pass 2: M = exp((minv-t)/eps) -> swizzled bf16 LDS + fused fp32 rowsum ----
        #pragma unroll
        for (int j = 0; j < 64; ++j) {
            float4 t = c[j];
            float m0 = __expf((minv - t.x) * inv_eps);
            float m1 = __expf((minv - t.y) * inv_eps);
            float m2 = __expf((minv - t.z) * inv_eps);
            float m3 = __expf((minv - t.w) * inv_eps);
            // word index r = row>>1 = j; byte half = row&1 = half
            ((unsigned short*)&Mw[w][((cb + 0) << 6) + (j ^ swz(cb + 0))])[half] = bf16_bits(m0);
            ((unsigned short*)&Mw[w][((cb + 1) << 6) + (j ^ swz(cb + 1))])[half] = bf16_bits(m1);
            ((unsigned short*)&Mw[w][((cb + 2) << 6) + (j ^ swz(cb + 2))])[half] = bf16_bits(m2);
            ((unsigned short*)&Mw[w][((cb + 3) << 6) + (j ^ swz(cb + 3))])[half] = bf16_bits(m3);
            float rs = half_sum32((m0 + m1) + (m2 + m3));   // per-half full-row sum
            if ((l & 31) == 0) grow[w][2 * j + half] = rs * (1.0f / (float)K);  // h_0 = rowsum/K
        }

        // ---- prefetch next example into the now-dead c[] registers; these 64 loads
        //      stay in flight through the entire FW phase (~5 us of latency cover) ----
        if (q + 1 < EPW) {
            const float* Cb_n = C + (size_t)(ex + 1) * (K * K);
            #pragma unroll
            for (int j = 0; j < 64; ++j)
                c[j] = *reinterpret_cast<const float4*>(Cb_n + 4 * l + 256 * j);
            s_l[w][l]      = scores[(ex + 1) * K + l];        // s_l unread until next iter
            s_l[w][l + 64] = scores[(ex + 1) * K + 64 + l];
        }

        // ---- Frank-Wolfe (whole wave): h' = (1-step)h + step*M[:,idx]; it=0 resets FP ----
        float g0, g1;
        {
            float2 g = *reinterpret_cast<const float2*>(&grow[w][2 * l]);
            g0 = g.x; g1 = g.y;
        }
        float a0 = 1.0f / K, a1 = 1.0f / K;
        #pragma unroll 1
        for (int it = 0; it < FW_ITERS; ++it) {
            const float v = wave_fmin_all(fminf(g0, g1));
            unsigned long long b0 = __ballot(g0 == v);
            unsigned long long b1 = __ballot(g1 == v);
            int i0 = b0 ? 2 * (int)__builtin_ctzll(b0)     : 0x7fffffff;
            int i1 = b1 ? 2 * (int)__builtin_ctzll(b1) + 1 : 0x7fffffff;
            const int idx = min(i0, i1);          // first-index tie-break

            const float step = 2.0f / (float)(it + 2);
            const float om = 1.0f - step;
            a0 *= om; a1 *= om;
            if (2 * l == idx)     a0 += step;
            if (2 * l + 1 == idx) a1 += step;
            // one conflict-free b32: bf16 M[2l][idx] (lo) and M[2l+1][idx] (hi)
            unsigned uw = Mw[w][(idx << 6) + (l ^ swz(idx))];
            g0 = om * g0 + step * __uint_as_float(uw << 16);
            g1 = om * g1 + step * __uint_as_float(uw & 0xffff0000u);
        }

        // ---- val = alpha^T M alpha = alpha . h  (h maintained exactly by FW) ----
        float valp = a0 * g0 + a1 * g1;
        #pragma unroll
        for (int m = 1; m < 64; m <<= 1) valp += __shfl_xor(valp, m, 64);
        if (l == 0) {
            // conjugate = -eps*(log(val+1e-12) + shift), shift = -minv/eps -> -eps*log(..)+minv
            out_partial[ex] = -eps * logf(valp + 1e-12f) + minv - f_y;
        }
    }
}

__global__ __launch_bounds__(256) void cacis_reduce(
    const float* __restrict__ part, float* __restrict__ out)
{
    __shared__ float red[4];
    const int tid = threadIdx.x;
    float acc = 0.f;
    for (int i = tid; i < NB; i += 256) acc += part[i];
    #pragma unroll
    for (int m = 1; m < 64; m <<= 1) acc += __shfl_xor(acc, m, 64);
    if ((tid & 63) == 0) red[tid >> 6] = acc;
    __syncthreads();
    if (tid == 0) out[0] = ((red[0] + red[1]) + (red[2] + red[3])) * (1.0f / (float)NB);
}

extern "C" void kernel_launch(void* const* d_in, const int* in_sizes, int n_in,
                              void* d_out, int out_size, void* d_ws, size_t ws_size,
                              hipStream_t stream) {
    const float* scores  = (const float*)d_in[0];
    const float* C       = (const float*)d_in[1];
    const int*   targets = (const int*)d_in[2];
    float* out  = (float*)d_out;
    float* part = (float*)d_ws;   // NB floats = 16 KB

    cacis_main<<<NBLK, WPB * 64, 0, stream>>>(scores, C, targets, part);
    cacis_reduce<<<1, 256, 0, stream>>>(part, out);
}

// Round 10
// 140.187 us; speedup vs baseline: 1.5926x; 1.5926x over previous
//
#include <hip/hip_runtime.h>
#include <hip/hip_bf16.h>

#define K 128
#define NB 4096
#define EPB 4                  // examples per persistent block
#define NBLK (NB / EPB)        // 1024 blocks = 4/CU resident
#define FW_ITERS 50

// ---------- DPP cross-lane helpers (validated rounds 3-9, absmax 0.0) ----------
template<int CTRL>
__device__ __forceinline__ float dpp_fmin(float v) {
    int s = __builtin_amdgcn_update_dpp(__float_as_int(v), __float_as_int(v), CTRL, 0xF, 0xF, false);
    return fminf(v, __int_as_float(s));
}
template<int CTRL>
__device__ __forceinline__ float dpp_fadd(float v) {
    int s = __builtin_amdgcn_update_dpp(__float_as_int(v), __float_as_int(v), CTRL, 0xF, 0xF, false);
    return v + __int_as_float(s);
}

__device__ __forceinline__ float wave_fmin_all(float v) {
    v = dpp_fmin<0xB1>(v);   // quad_perm xor1
    v = dpp_fmin<0x4E>(v);   // quad_perm xor2
    v = dpp_fmin<0x124>(v);  // row_ror:4
    v = dpp_fmin<0x128>(v);  // row_ror:8 -> per-16 min
#if __has_builtin(__builtin_amdgcn_permlane16_swap)
    {
        auto r = __builtin_amdgcn_permlane16_swap(__float_as_int(v), __float_as_int(v), false, false);
        v = fminf(__int_as_float(r[0]), __int_as_float(r[1]));
    }
#else
    v = fminf(v, __shfl_xor(v, 16, 64));
#endif
#if __has_builtin(__builtin_amdgcn_permlane32_swap)
    {
        auto r = __builtin_amdgcn_permlane32_swap(__float_as_int(v), __float_as_int(v), false, false);
        v = fminf(__int_as_float(r[0]), __int_as_float(r[1]));
    }
#else
    v = fminf(v, __shfl_xor(v, 32, 64));
#endif
    return v;
}

// per-32-lane-half sum (lanes 0-31 / 32-63 independently), result in all lanes
__device__ __forceinline__ float half_sum32(float v) {
    v = dpp_fadd<0xB1>(v);
    v = dpp_fadd<0x4E>(v);
    v = dpp_fadd<0x124>(v);
    v = dpp_fadd<0x128>(v);
#if __has_builtin(__builtin_amdgcn_permlane16_swap)
    {
        auto r = __builtin_amdgcn_permlane16_swap(__float_as_int(v), __float_as_int(v), false, false);
        v = __int_as_float(r[0]) + __int_as_float(r[1]);
    }
#else
    v = v + __shfl_xor(v, 16, 64);
#endif
    return v;
}

__device__ __forceinline__ unsigned short bf16_bits(float f) {
    __hip_bfloat16 h = __float2bfloat16(f);
    return *reinterpret_cast<unsigned short*>(&h);
}

// XOR swizzle: word(r, col) = col*64 + (r ^ swz(col)); word packs bf16 rows (2r,2r+1) at col.
// Build stores and FW column gather are <=2 lanes/bank (0 conflicts measured, r5-r9).
__device__ __forceinline__ int swz(int col) {
    return ((col >> 2) + ((col & 3) << 3)) & 31;
}

// LDS-only barrier: fences LDS producer->consumer edges WITHOUT draining vmcnt,
// so prefetched global loads (private VGPR destinations) stay in flight across it.
// (Validated r7: absmax 0.0 with this sync pattern.)
__device__ __forceinline__ void barrier_lds() {
    asm volatile("s_waitcnt lgkmcnt(0)" ::: "memory");
    __builtin_amdgcn_s_barrier();
    asm volatile("" ::: "memory");
}

__global__ __launch_bounds__(256, 2) void cacis_main(
    const float* __restrict__ scores,
    const float* __restrict__ C,
    const int* __restrict__ targets,
    float* __restrict__ out_partial)
{
    __shared__ unsigned int Mw[K * 64];        // 32 KB swizzled pair-packed bf16
    __shared__ __align__(16) float s_lds[K];
    __shared__ __align__(16) float grow[K];
    __shared__ float red[4][4];

    const int b = blockIdx.x;
    const int tid = threadIdx.x;
    const int w = tid >> 6;
    const int lane = tid & 63;
    const int cb = 4 * (tid & 31);

    // ---- prologue: issue example 0's loads; targets for all 4 examples ----
    float4 c[16];
    float sreg;
    int4 tgts;
    {
        const float* Cb = C + (size_t)(b * EPB) * (K * K);
        #pragma unroll
        for (int j = 0; j < 16; ++j)
            c[j] = *reinterpret_cast<const float4*>(Cb + 4 * tid + 1024 * j);
        if (tid < K) sreg = scores[(b * EPB) * K + tid];
        if (tid == 0) tgts = *reinterpret_cast<const int4*>(&targets[b * EPB]);
    }

    #pragma unroll 1
    for (int ee = 0; ee < EPB; ++ee) {
        const int ex = b * EPB + ee;

        if (tid < K) s_lds[tid] = sreg;        // waits only sreg's vmcnt
        barrier_lds();                          // (1) scores staged

        float f_y = 0.f;
        if (tid == 0) {
            const int tgt = (ee == 0) ? tgts.x : (ee == 1) ? tgts.y : (ee == 2) ? tgts.z : tgts.w;
            f_y = s_lds[tgt];                  // s_lds stable until next stage (barrier-ordered)
        }

        // ---- pass 1: t = s_i + s_j + C; partials sumC / trace / min ----
        float sc0, sc1, sc2, sc3;
        {
            float4 s4 = *reinterpret_cast<const float4*>(&s_lds[cb]);
            sc0 = s4.x; sc1 = s4.y; sc2 = s4.z; sc3 = s4.w;
        }
        float sumC = 0.f, trace = 0.f, minv = 1e30f;
        #pragma unroll
        for (int j = 0; j < 16; ++j) {
            const int row = 8 * j + (tid >> 5);
            const float sr = s_lds[row];
            float4 v = c[j];                   // per-j vmcnt waits: load tail overlaps here
            sumC += (v.x + v.y) + (v.z + v.w);
            const int d = row - cb;
            if (d >= 0 && d < 4)
                trace += (d == 0) ? v.x : (d == 1) ? v.y : (d == 2) ? v.z : v.w;
            float t0 = sr + sc0 + v.x;
            float t1 = sr + sc1 + v.y;
            float t2 = sr + sc2 + v.z;
            float t3 = sr + sc3 + v.w;
            c[j] = make_float4(t0, t1, t2, t3);
            minv = fminf(minv, fminf(fminf(t0, t1), fminf(t2, t3)));
        }
        #pragma unroll
        for (int m = 1; m < 64; m <<= 1) {
            sumC  += __shfl_xor(sumC, m, 64);
            trace += __shfl_xor(trace, m, 64);
            minv   = fminf(minv, __shfl_xor(minv, m, 64));
        }
        if (lane == 0) { red[w][0] = sumC; red[w][1] = trace; red[w][2] = minv; }
        barrier_lds();                          // (2) partials visible
        sumC  = (red[0][0] + red[1][0]) + (red[2][0] + red[3][0]);
        trace = (red[0][1] + red[1][1]) + (red[2][1] + red[3][1]);
        minv  = fminf(fminf(red[0][2], red[1][2]), fminf(red[2][2], red[3][2]));

        const float eps = fmaxf((sumC - trace) * (1.0f / (float)(K * (K - 1))), 1e-8f); // EPS_SCALE=1
        const float inv_eps = 1.0f / eps;

        // ---- M = exp((minv-t)/eps): swizzled bf16 to LDS + fused fp32 rowsum ----
        #pragma unroll
        for (int j = 0; j < 16; ++j) {
            const int row = 8 * j + (tid >> 5);
            float4 t = c[j];
            float m0 = __expf((minv - t.x) * inv_eps);
            float m1 = __expf((minv - t.y) * inv_eps);
            float m2 = __expf((minv - t.z) * inv_eps);
            float m3 = __expf((minv - t.w) * inv_eps);
            const int r = row >> 1, hh = row & 1;
            ((unsigned short*)&Mw[((cb + 0) << 6) + (r ^ swz(cb + 0))])[hh] = bf16_bits(m0);
            ((unsigned short*)&Mw[((cb + 1) << 6) + (r ^ swz(cb + 1))])[hh] = bf16_bits(m1);
            ((unsigned short*)&Mw[((cb + 2) << 6) + (r ^ swz(cb + 2))])[hh] = bf16_bits(m2);
            ((unsigned short*)&Mw[((cb + 3) << 6) + (r ^ swz(cb + 3))])[hh] = bf16_bits(m3);
            float rs = half_sum32((m0 + m1) + (m2 + m3));   // lanes 0-31 own full row
            if ((lane & 31) == 0) grow[row] = rs * (1.0f / (float)K);   // h_0 = rowsum/K
        }

        // ---- prefetch next example into the now-dead c[] registers; loads stay in
        //      flight through FW (raw barriers never drain vmcnt) ----
        if (ee + 1 < EPB) {
            const float* Cb_n = C + (size_t)(ex + 1) * (K * K);
            #pragma unroll
            for (int j = 0; j < 16; ++j)
                c[j] = *reinterpret_cast<const float4*>(Cb_n + 4 * tid + 1024 * j);
            if (tid < K) sreg = scores[(ex + 1) * K + tid];
        }
        barrier_lds();                          // (3) Mw + grow visible

        // ---- Frank-Wolfe (wave 0): h' = (1-step)h + step*M[:,idx]; val = alpha.h ----
        if (w == 0) {
            const int l = lane;
            float g0 = grow[2 * l], g1 = grow[2 * l + 1];
            float a0 = 1.0f / K, a1 = 1.0f / K;
            #pragma unroll 1
            for (int it = 0; it < FW_ITERS; ++it) {
                const float v = wave_fmin_all(fminf(g0, g1));
                unsigned long long b0 = __ballot(g0 == v);
                unsigned long long b1 = __ballot(g1 == v);
                int i0 = b0 ? 2 * (int)__builtin_ctzll(b0)     : 0x7fffffff;
                int i1 = b1 ? 2 * (int)__builtin_ctzll(b1) + 1 : 0x7fffffff;
                const int idx = min(i0, i1);          // first-index tie-break

                const float step = 2.0f / (float)(it + 2);
                const float om = 1.0f - step;
                a0 *= om; a1 *= om;
                if (2 * l == idx)     a0 += step;
                if (2 * l + 1 == idx) a1 += step;
                // one conflict-free b32: bf16 M[2l][idx] (lo) and M[2l+1][idx] (hi)
                unsigned uw = Mw[(idx << 6) + (l ^ swz(idx))];
                g0 = om * g0 + step * __uint_as_float(uw << 16);
                g1 = om * g1 + step * __uint_as_float(uw & 0xffff0000u);
            }
            // val = alpha^T M alpha = alpha . h (h maintained exactly; r9-validated)
            float valp = a0 * g0 + a1 * g1;
            #pragma unroll
            for (int m = 1; m < 64; m <<= 1) valp += __shfl_xor(valp, m, 64);
            if (l == 0) {
                // conjugate = -eps*(log(val+1e-12) + shift), shift = -minv/eps
                out_partial[ex] = -eps * logf(valp + 1e-12f) + minv - f_y;
            }
        }
        // waves 1-3 run ahead to the next stage barrier; wave 0 joins after FW.
        // s_lds[64..127] overwrite by wave 1 is safe: old values dead (f_y read above).
    }
}

__global__ __launch_bounds__(256) void cacis_reduce(
    const float* __restrict__ part, float* __restrict__ out)
{
    __shared__ float red[4];
    const int tid = threadIdx.x;
    float acc = 0.f;
    for (int i = tid; i < NB; i += 256) acc += part[i];
    #pragma unroll
    for (int m = 1; m < 64; m <<= 1) acc += __shfl_xor(acc, m, 64);
    if ((tid & 63) == 0) red[tid >> 6] = acc;
    __syncthreads();
    if (tid == 0) out[0] = ((red[0] + red[1]) + (red[2] + red[3])) * (1.0f / (float)NB);
}

extern "C" void kernel_launch(void* const* d_in, const int* in_sizes, int n_in,
                              void* d_out, int out_size, void* d_ws, size_t ws_size,
                              hipStream_t stream) {
    const float* scores  = (const float*)d_in[0];
    const float* C       = (const float*)d_in[1];
    const int*   targets = (const int*)d_in[2];
    float* out  = (float*)d_out;
    float* part = (float*)d_ws;   // NB floats = 16 KB

    cacis_main<<<NBLK, 256, 0, stream>>>(scores, C, targets, part);
    cacis_reduce<<<1, 256, 0, stream>>>(part, out);
}

// Round 11
// 87.406 us; speedup vs baseline: 2.5542x; 1.6039x over previous
//
#include <hip/hip_runtime.h>
#include <hip/hip_bf16.h>

#define K 128
#define NB 4096
#define FW_ITERS 50

// ---------- DPP cross-lane helpers (validated rounds 3-10, absmax 0.0) ----------
template<int CTRL>
__device__ __forceinline__ float dpp_fmin(float v) {
    int s = __builtin_amdgcn_update_dpp(__float_as_int(v), __float_as_int(v), CTRL, 0xF, 0xF, false);
    return fminf(v, __int_as_float(s));
}
template<int CTRL>
__device__ __forceinline__ float dpp_fadd(float v) {
    int s = __builtin_amdgcn_update_dpp(__float_as_int(v), __float_as_int(v), CTRL, 0xF, 0xF, false);
    return v + __int_as_float(s);
}

__device__ __forceinline__ float wave_fmin_all(float v) {
    v = dpp_fmin<0xB1>(v);   // quad_perm xor1
    v = dpp_fmin<0x4E>(v);   // quad_perm xor2
    v = dpp_fmin<0x124>(v);  // row_ror:4
    v = dpp_fmin<0x128>(v);  // row_ror:8 -> per-16 min
#if __has_builtin(__builtin_amdgcn_permlane16_swap)
    {
        auto r = __builtin_amdgcn_permlane16_swap(__float_as_int(v), __float_as_int(v), false, false);
        v = fminf(__int_as_float(r[0]), __int_as_float(r[1]));
    }
#else
    v = fminf(v, __shfl_xor(v, 16, 64));
#endif
#if __has_builtin(__builtin_amdgcn_permlane32_swap)
    {
        auto r = __builtin_amdgcn_permlane32_swap(__float_as_int(v), __float_as_int(v), false, false);
        v = fminf(__int_as_float(r[0]), __int_as_float(r[1]));
    }
#else
    v = fminf(v, __shfl_xor(v, 32, 64));
#endif
    return v;
}

// per-32-lane-half sum (lanes 0-31 / 32-63 independently), result in all lanes
__device__ __forceinline__ float half_sum32(float v) {
    v = dpp_fadd<0xB1>(v);
    v = dpp_fadd<0x4E>(v);
    v = dpp_fadd<0x124>(v);
    v = dpp_fadd<0x128>(v);
#if __has_builtin(__builtin_amdgcn_permlane16_swap)
    {
        auto r = __builtin_amdgcn_permlane16_swap(__float_as_int(v), __float_as_int(v), false, false);
        v = __int_as_float(r[0]) + __int_as_float(r[1]);
    }
#else
    v = v + __shfl_xor(v, 16, 64);
#endif
    return v;
}

__device__ __forceinline__ unsigned short bf16_bits(float f) {
    __hip_bfloat16 h = __float2bfloat16(f);
    return *reinterpret_cast<unsigned short*>(&h);
}

// XOR swizzle: word(r, col) = col*64 + (r ^ swz(col)); word packs bf16 rows (2r,2r+1) at col.
// Build stores and FW column gather are <=2 lanes/bank (0 conflicts measured, r5-r10).
__device__ __forceinline__ int swz(int col) {
    return ((col >> 2) + ((col & 3) << 3)) & 31;
}

__global__ __launch_bounds__(256) void cacis_main(
    const float* __restrict__ scores,
    const float* __restrict__ C,
    const int* __restrict__ targets,
    float* __restrict__ out_partial)
{
    __shared__ unsigned int Mw[K * 64];        // 32 KB swizzled pair-packed bf16
    __shared__ __align__(16) float s_lds[K];
    __shared__ __align__(16) float grow[K];
    __shared__ float red[4][4];

    const int b = blockIdx.x;
    const int tid = threadIdx.x;
    const int w = tid >> 6;
    const int lane = tid & 63;
    const int cb = 4 * (tid & 31);

    if (tid < K) s_lds[tid] = scores[b * K + tid];
    __syncthreads();

    // Thread t owns float4 chunks: row_j = 8*j + (t>>5), cols [4*(t&31), +4) -> coalesced
    const float* Cb = C + (size_t)b * (K * K);
    float4 c[16];
    float sc0, sc1, sc2, sc3;
    {
        float4 s4 = *reinterpret_cast<const float4*>(&s_lds[cb]);
        sc0 = s4.x; sc1 = s4.y; sc2 = s4.z; sc3 = s4.w;
    }

    #pragma unroll
    for (int j = 0; j < 16; ++j)
        c[j] = *reinterpret_cast<const float4*>(Cb + 4 * tid + 1024 * j);

    // ---- pass 1: t = s_i + s_j + C; partials sumC / trace / min ----
    float sumC = 0.f, trace = 0.f, minv = 1e30f;
    #pragma unroll
    for (int j = 0; j < 16; ++j) {
        const int row = 8 * j + (tid >> 5);
        const float sr = s_lds[row];
        float4 v = c[j];
        sumC += (v.x + v.y) + (v.z + v.w);
        const int d = row - cb;
        if (d >= 0 && d < 4)
            trace += (d == 0) ? v.x : (d == 1) ? v.y : (d == 2) ? v.z : v.w;
        float t0 = sr + sc0 + v.x;
        float t1 = sr + sc1 + v.y;
        float t2 = sr + sc2 + v.z;
        float t3 = sr + sc3 + v.w;
        c[j] = make_float4(t0, t1, t2, t3);
        minv = fminf(minv, fminf(fminf(t0, t1), fminf(t2, t3)));
    }

    // block reduce (sumC, trace, minv)
    #pragma unroll
    for (int m = 1; m < 64; m <<= 1) {
        sumC  += __shfl_xor(sumC, m, 64);
        trace += __shfl_xor(trace, m, 64);
        minv   = fminf(minv, __shfl_xor(minv, m, 64));
    }
    if (lane == 0) { red[w][0] = sumC; red[w][1] = trace; red[w][2] = minv; }
    __syncthreads();
    sumC  = (red[0][0] + red[1][0]) + (red[2][0] + red[3][0]);
    trace = (red[0][1] + red[1][1]) + (red[2][1] + red[3][1]);
    minv  = fminf(fminf(red[0][2], red[1][2]), fminf(red[2][2], red[3][2]));

    const float eps = fmaxf((sumC - trace) * (1.0f / (float)(K * (K - 1))), 1e-8f); // EPS_SCALE=1
    const float inv_eps = 1.0f / eps;

    // ---- M = exp((minv - t)/eps): swizzled bf16 to LDS + fused fp32 rowsum ----
    // For wave w: lanes 0-31 own full row 8j+2w, lanes 32-63 own row 8j+2w+1.
    #pragma unroll
    for (int j = 0; j < 16; ++j) {
        const int row = 8 * j + (tid >> 5);
        float4 t = c[j];
        float m0 = __expf((minv - t.x) * inv_eps);
        float m1 = __expf((minv - t.y) * inv_eps);
        float m2 = __expf((minv - t.z) * inv_eps);
        float m3 = __expf((minv - t.w) * inv_eps);
        const int r = row >> 1, hh = row & 1;
        ((unsigned short*)&Mw[((cb + 0) << 6) + (r ^ swz(cb + 0))])[hh] = bf16_bits(m0);
        ((unsigned short*)&Mw[((cb + 1) << 6) + (r ^ swz(cb + 1))])[hh] = bf16_bits(m1);
        ((unsigned short*)&Mw[((cb + 2) << 6) + (r ^ swz(cb + 2))])[hh] = bf16_bits(m2);
        ((unsigned short*)&Mw[((cb + 3) << 6) + (r ^ swz(cb + 3))])[hh] = bf16_bits(m3);
        float rs = half_sum32((m0 + m1) + (m2 + m3));
        if ((lane & 31) == 0) grow[row] = rs * (1.0f / (float)K);   // h_0 = rowsum/K
    }
    __syncthreads();    // Mw + grow visible to wave 0

    // ---- waves 1-3 are done: exit, freeing SIMD issue slots for other blocks.
    //      (s_barrier releases on all *live* waves; no further barriers below.) ----
    if (w != 0) return;

    // ---- Frank-Wolfe (wave 0): h' = (1-step)h + step*M[:,idx]; it=0 step=1 resets FP ----
    const int l = lane;
    float g0, g1;
    {
        float2 g = *reinterpret_cast<const float2*>(&grow[2 * l]);
        g0 = g.x; g1 = g.y;
    }
    float a0 = 1.0f / K, a1 = 1.0f / K;
    #pragma unroll 1
    for (int it = 0; it < FW_ITERS; ++it) {
        const float v = wave_fmin_all(fminf(g0, g1));
        unsigned long long b0 = __ballot(g0 == v);
        unsigned long long b1 = __ballot(g1 == v);
        int i0 = b0 ? 2 * (int)__builtin_ctzll(b0)     : 0x7fffffff;
        int i1 = b1 ? 2 * (int)__builtin_ctzll(b1) + 1 : 0x7fffffff;
        const int idx = min(i0, i1);          // first-index tie-break

        const float step = 2.0f / (float)(it + 2);
        const float om = 1.0f - step;
        a0 *= om; a1 *= om;
        if (2 * l == idx)     a0 += step;
        if (2 * l + 1 == idx) a1 += step;
        // one conflict-free b32: bf16 M[2l][idx] (lo half) and M[2l+1][idx] (hi half)
        unsigned uw = Mw[(idx << 6) + (l ^ swz(idx))];
        g0 = om * g0 + step * __uint_as_float(uw << 16);
        g1 = om * g1 + step * __uint_as_float(uw & 0xffff0000u);
    }

    // ---- val = alpha^T M alpha = alpha . h  (h maintained exactly; r9/r10-validated) ----
    float valp = a0 * g0 + a1 * g1;
    #pragma unroll
    for (int m = 1; m < 64; m <<= 1) valp += __shfl_xor(valp, m, 64);
    if (l == 0) {
        const int tgt = targets[b];
        // conjugate = -eps*(log(val+1e-12) + shift), shift = -minv/eps -> -eps*log(..) + minv
        out_partial[b] = -eps * logf(valp + 1e-12f) + minv - s_lds[tgt];
    }
}

__global__ __launch_bounds__(256) void cacis_reduce(
    const float* __restrict__ part, float* __restrict__ out)
{
    __shared__ float red[4];
    const int tid = threadIdx.x;
    float acc = 0.f;
    for (int i = tid; i < NB; i += 256) acc += part[i];
    #pragma unroll
    for (int m = 1; m < 64; m <<= 1) acc += __shfl_xor(acc, m, 64);
    if ((tid & 63) == 0) red[tid >> 6] = acc;
    __syncthreads();
    if (tid == 0) out[0] = ((red[0] + red[1]) + (red[2] + red[3])) * (1.0f / (float)NB);
}

extern "C" void kernel_launch(void* const* d_in, const int* in_sizes, int n_in,
                              void* d_out, int out_size, void* d_ws, size_t ws_size,
                              hipStream_t stream) {
    const float* scores  = (const float*)d_in[0];
    const float* C       = (const float*)d_in[1];
    const int*   targets = (const int*)d_in[2];
    float* out  = (float*)d_out;
    float* part = (float*)d_ws;   // NB floats = 16 KB

    cacis_main<<<NB, 256, 0, stream>>>(scores, C, targets, part);
    cacis_reduce<<<1, 256, 0, stream>>>(part, out);
}